// Round 2
// baseline (181.373 us; speedup 1.0000x reference)
//
#include <hip/hip_runtime.h>
#include <hip/hip_bf16.h>
#include <cstdint>
#include <cstddef>

// Round 12: k_attn barrier-free. The old LDS staging was a per-lane identity
// map (each lane read back exactly the bytes its own async_cp16 staged), so
// LDS was acting purely as a prefetch buffer at the cost of a per-iter
// __syncthreads() vmcnt(0)+lgkmcnt(0) drain coupling all 4 waves. Replaced
// with direct global->VGPR fragment loads, register double-buffered one iter
// ahead. No barriers / no LDS in the main loop; LDS (8.7 KB) only for the
// final split-K combine. k_prep/k_qkv/k_out unchanged.

#define NB 4
#define CIN 256
#define CHID 128
#define HEADS 4
#define CHEAD 32
#define NPOS 4096      // 64*64
#define BH 16          // NB*HEADS
#define NTOT 16384     // NB*NPOS
#define QKV_O 384
// 32^-0.5 * log2(e): Q pre-scaled so softmax logits feed exp2 directly
#define QSCALE_LOG2E 0.2550348229f

typedef float f32x2 __attribute__((ext_vector_type(2)));
typedef float f32x4 __attribute__((ext_vector_type(4)));
typedef float f32x16 __attribute__((ext_vector_type(16)));
typedef short s16x8 __attribute__((ext_vector_type(8)));

static __device__ __forceinline__ unsigned short f2bf(float f) {
    union { float f; unsigned u; } v; v.f = f;
    unsigned r = v.u + 0x7FFFu + ((v.u >> 16) & 1u);
    return (unsigned short)(r >> 16);
}

static __device__ __forceinline__ unsigned int pk2bf(float a, float b) {
    union { __hip_bfloat162 h; unsigned int u; } c;
    c.h = __float22bfloat162_rn(float2{a, b});
    return c.u;
}

// Exchange upper-half lanes of a with lower-half lanes of b (gfx950 VALU op).
static __device__ __forceinline__ void plswap(unsigned& a, unsigned& b) {
#if __has_builtin(__builtin_amdgcn_permlane32_swap)
    auto r = __builtin_amdgcn_permlane32_swap((int)a, (int)b, false, false);
    a = (unsigned)r[0];
    b = (unsigned)r[1];
#else
    int hh = (threadIdx.x >> 5) & 1;
    unsigned ta = (unsigned)__shfl_xor((int)a, 32);
    unsigned tb = (unsigned)__shfl_xor((int)b, 32);
    unsigned na = hh ? tb : a;
    unsigned nb = hh ? b : ta;
    a = na; b = nb;
#endif
}

static __device__ __forceinline__ s16x8 mk8(unsigned a, unsigned b, unsigned c, unsigned d) {
    union { unsigned u[4]; s16x8 v; } x;
    x.u[0] = a; x.u[1] = b; x.u[2] = c; x.u[3] = d;
    return x.v;
}

static __device__ __forceinline__ void async_cp16(const void* g, void* l) {
    __builtin_amdgcn_global_load_lds((const __attribute__((address_space(1))) unsigned int*)g,
                                     (__attribute__((address_space(3))) unsigned int*)l, 16, 0, 0);
}

#define MFMA32(a, b, c) __builtin_amdgcn_mfma_f32_32x32x16_bf16(a, b, c, 0, 0, 0)

// ---------------- kernel 1: transpose x -> xT bf16, fused weight convert ----------------
#define TBLOCKS (NB * (CIN / 32) * (NPOS / 32))   // 4096
__global__ __launch_bounds__(256) void k_prep(const float* __restrict__ x,
                                              unsigned short* __restrict__ xT,
                                              const float* __restrict__ wqkv,
                                              const float* __restrict__ wout,
                                              unsigned short* __restrict__ wqkv_bf,
                                              unsigned short* __restrict__ wout_bf) {
    if (blockIdx.x >= TBLOCKS) {   // weight-convert tail blocks
        int i = (blockIdx.x - TBLOCKS) * 256 + threadIdx.x;
        if (i < QKV_O * CIN) wqkv_bf[i] = f2bf(wqkv[i]);
        if (i < CIN * CHID)  wout_bf[i] = f2bf(wout[i]);
        return;
    }
    __shared__ float tile[32][33];
    const int ntiles = NPOS / 32;   // 128
    const int ctiles = CIN / 32;    // 8
    int b   = blockIdx.x / (ntiles * ctiles);
    int rem = blockIdx.x % (ntiles * ctiles);
    int ct = rem / ntiles;
    int nt = rem % ntiles;
    int c0 = ct * 32, n0 = nt * 32;
    int tc = threadIdx.x / 32;
    int tn = threadIdx.x % 32;
    const float* xb = x + (size_t)b * CIN * NPOS;
#pragma unroll
    for (int it = 0; it < 4; ++it) {
        int c = tc + it * 8;
        tile[c][tn] = xb[(size_t)(c0 + c) * NPOS + n0 + tn];
    }
    __syncthreads();
    unsigned short* xTb = xT + (size_t)b * NPOS * CIN;
#pragma unroll
    for (int it = 0; it < 4; ++it) {
        int n = tc + it * 8;
        xTb[(size_t)(n0 + n) * CIN + c0 + tn] = f2bf(tile[tn][n]);
    }
}

// ---------------- kernel 2: QKV projection GEMM, LDS-staged ----------------
// mt==0 -> pure Q, mt==1 -> pure K, mt==2 -> pure V (LDS-transposed epilogue)
__global__ __launch_bounds__(256, 4) void k_qkv(const unsigned short* __restrict__ wq,
                                                const unsigned short* __restrict__ xT,
                                                unsigned short* __restrict__ Q,
                                                unsigned short* __restrict__ K,
                                                unsigned short* __restrict__ V) {
    __shared__ __align__(16) unsigned char smem[2 * 12288];   // 24 KB
    int mt = blockIdx.x % 3;
    int nt = blockIdx.x / 3;
    int wid = threadIdx.x >> 6, lane = threadIdx.x & 63;
    int quad = lane >> 4, low4 = lane & 15;
    int o0 = mt * 128, n0 = nt * 64;
    int lb = lane * 16;

    const unsigned short* srcA0 = wq + (size_t)(o0 + wid * 32 + low4) * CIN + quad * 8;
    const unsigned short* srcA1 = srcA0 + 16 * CIN;
    const unsigned short* srcB  = xT + (size_t)(n0 + wid * 16 + low4) * CIN + quad * 8;
    int dA0 = wid * 2048, dA1 = dA0 + 1024, dB = 8192 + wid * 1024;

    async_cp16(srcA0, smem + dA0 + lb);
    async_cp16(srcA1, smem + dA1 + lb);
    async_cp16(srcB,  smem + dB  + lb);
    __syncthreads();

    f32x4 acc[2][4] = {};
    for (int c = 0; c < 8; ++c) {
        if (c < 7) {
            unsigned char* nxt = smem + ((c + 1) & 1) * 12288;
            async_cp16(srcA0 + (c + 1) * 32, nxt + dA0 + lb);
            async_cp16(srcA1 + (c + 1) * 32, nxt + dA1 + lb);
            async_cp16(srcB  + (c + 1) * 32, nxt + dB  + lb);
        }
        const unsigned char* cur = smem + (c & 1) * 12288;
        s16x8 a0 = *(const s16x8*)(cur + wid * 2048 + lb);
        s16x8 a1 = *(const s16x8*)(cur + wid * 2048 + 1024 + lb);
#pragma unroll
        for (int j = 0; j < 4; ++j) {
            s16x8 bj = *(const s16x8*)(cur + 8192 + j * 1024 + lb);
            acc[0][j] = __builtin_amdgcn_mfma_f32_16x16x32_bf16(a0, bj, acc[0][j], 0, 0, 0);
            acc[1][j] = __builtin_amdgcn_mfma_f32_16x16x32_bf16(a1, bj, acc[1][j], 0, 0, 0);
        }
        __syncthreads();
    }

    if (mt < 2) {
        unsigned short* dst = (mt == 0) ? Q : K;
        float sc = (mt == 0) ? QSCALE_LOG2E : 1.0f;
#pragma unroll
        for (int i = 0; i < 2; ++i) {
            int ol = wid * 32 + i * 16 + quad * 4;
            int head = ol >> 5, ch = ol & 31;
#pragma unroll
            for (int j = 0; j < 4; ++j) {
                int nG = n0 + j * 16 + low4;
                int b = nG >> 12, n = nG & 4095;
                f32x4 v = acc[i][j];
                unsigned long long d =
                    (unsigned long long)pk2bf(v[0] * sc, v[1] * sc) |
                    ((unsigned long long)pk2bf(v[2] * sc, v[3] * sc) << 32);
                *(unsigned long long*)(dst + ((size_t)(b * 4 + head) * NPOS + n) * 32 + ch) = d;
            }
        }
    } else {
        // V: transpose 128(ch) x 64(n) through LDS, store V^T coalesced b128
        unsigned short* vt = (unsigned short*)smem;   // [128][80] shorts (20 KB), rows 16B-aligned
#pragma unroll
        for (int i = 0; i < 2; ++i) {
            int ol = wid * 32 + i * 16 + quad * 4;
#pragma unroll
            for (int j = 0; j < 4; ++j) {
                int col = j * 16 + low4;
#pragma unroll
                for (int r = 0; r < 4; ++r) vt[(ol + r) * 80 + col] = f2bf(acc[i][j][r]);
            }
        }
        __syncthreads();
        int b = n0 >> 12, nbase = n0 & 4095;
#pragma unroll
        for (int rep = 0; rep < 4; ++rep) {
            int idx = rep * 256 + threadIdx.x;
            int row = idx >> 3, c8 = idx & 7;
            s16x8 val = *(const s16x8*)(vt + row * 80 + c8 * 8);
            int head = row >> 5, ch = row & 31;
            *(s16x8*)(V + ((size_t)((b * 4 + head) * 32 + ch)) * NPOS + nbase + c8 * 8) = val;
        }
    }
}

// ---------------- kernel 3: attention, 32 queries/wave, split-K x2, 1024 blocks ----------------
// Grid: qt(64) x bh(16), blockIdx = qt*16 + bh (same-bh blocks share an XCD;
// per-XCD K/V working set ~1 MB -> L2-resident). Block: 4 waves = qg(2) x
// kh(2). Main loop is BARRIER-FREE: each wave loads its own K/V fragments
// directly global->VGPR (per-lane addresses equal what the old LDS staging
// produced), register double-buffered one iteration ahead. LDS is used only
// for the final split-K combine. Load placement keeps peak live VGPR ~110:
// next-K issued after cur-K dies (post QK t1), next-V at iteration end.
__global__ __launch_bounds__(256, 4) void k_attn(const unsigned short* __restrict__ Q,
                                                 const unsigned short* __restrict__ K,
                                                 const unsigned short* __restrict__ V,
                                                 unsigned short* __restrict__ attnO) {
    __shared__ __align__(16) unsigned char smem[8704];   // 2 x (1024 oT + 64 lsum) floats
    int bh = blockIdx.x & 15;
    int qt = blockIdx.x >> 4;          // 0..63
    int wid = threadIdx.x >> 6;        // 0..3
    int lane = threadIdx.x & 63;
    int q5 = lane & 31, h = lane >> 5;
    int qg = wid & 1, kh = wid >> 1;
    int q0 = qt * 64 + qg * 32;
    int khk = kh * 2048;

    const unsigned short* Qp  = Q + (size_t)bh * NPOS * 32;
    const unsigned short* Kbh = K + (size_t)bh * NPOS * 32;
    const unsigned short* Vbh = V + (size_t)bh * 32 * NPOS;

    // Q B-frags (n=query q5, k=ch chunks 0..15 / 16..31)
    s16x8 bq0 = *(const s16x8*)(Qp + (size_t)(q0 + q5) * 32 + h * 8);
    s16x8 bq1 = *(const s16x8*)(Qp + (size_t)(q0 + q5) * 32 + 16 + h * 8);

    // Per-lane fragment base pointers (identical addresses to the old LDS
    // staging's per-lane pass-through).
    const unsigned short* pK = Kbh + (size_t)q5 * 32 + h * 8;   // + k0*32 + t*1024 + f*16
    const unsigned short* pV = Vbh + (size_t)q5 * NPOS + h * 8; // + k0 + c*16

#define LK(k0, t, f) (*(const s16x8*)(pK + (size_t)(k0) * 32 + (t) * 1024 + (f) * 16))
#define LV(k0, c)    (*(const s16x8*)(pV + (k0) + (c) * 16))

    f32x16 oT = {};
    f32x2 lacc0 = {0.0f, 0.0f}, lacc1 = {0.0f, 0.0f};

    // exp2 + bf16-pack + C->B-frag transform for one 32-key tile (register-only)
    auto softmax_tile = [&](const f32x16& s, s16x8& bplo, s16x8& bphi) {
        unsigned p[8];
#pragma unroll
        for (int i = 0; i < 8; ++i) {
            float e0 = __builtin_amdgcn_exp2f(s[2 * i]);
            float e1 = __builtin_amdgcn_exp2f(s[2 * i + 1]);
            f32x2 e = {e0, e1};
            if (i & 1) lacc0 += e;
            else       lacc1 += e;
            p[i] = pk2bf(e0, e1);
        }
        plswap(p[0], p[2]); plswap(p[1], p[3]);
        plswap(p[4], p[6]); plswap(p[5], p[7]);
        bplo = mk8(p[0], p[1], p[2], p[3]);
        bphi = mk8(p[4], p[5], p[6], p[7]);
    };

    // prologue: load iter-0 fragments
    s16x8 ak00 = LK(khk, 0, 0), ak01 = LK(khk, 0, 1);
    s16x8 ak10 = LK(khk, 1, 0), ak11 = LK(khk, 1, 1);
    s16x8 av00 = LV(khk, 0), av01 = LV(khk, 1);
    s16x8 av10 = LV(khk, 2), av11 = LV(khk, 3);

#pragma unroll 1
    for (int it = 0; it < 32; ++it) {
        int k0n = khk + ((it + 1) & 31) * 64;   // wrapped: last iter reloads k0 (discarded)

        // QK tile 0
        f32x16 s0 = {};
        s0 = MFMA32(ak00, bq0, s0);
        s0 = MFMA32(ak01, bq1, s0);
        s16x8 bplo0, bphi0;
        softmax_tile(s0, bplo0, bphi0);

        // QK tile 1
        f32x16 s1 = {};
        s1 = MFMA32(ak10, bq0, s1);
        s1 = MFMA32(ak11, bq1, s1);

        // cur-K dead -> prefetch next-K (covered by PV t0 + softmax t1 + PV t1)
        s16x8 nk00 = LK(k0n, 0, 0), nk01 = LK(k0n, 0, 1);
        s16x8 nk10 = LK(k0n, 1, 0), nk11 = LK(k0n, 1, 1);

        // PV tile 0
        oT = MFMA32(av00, bplo0, oT);
        oT = MFMA32(av01, bphi0, oT);

        s16x8 bplo1, bphi1;
        softmax_tile(s1, bplo1, bphi1);

        // PV tile 1
        oT = MFMA32(av10, bplo1, oT);
        oT = MFMA32(av11, bphi1, oT);

        // cur-V dead -> prefetch next-V (covered by next iter's QK+softmax t0/t1)
        s16x8 nv00 = LV(k0n, 0), nv01 = LV(k0n, 1);
        s16x8 nv10 = LV(k0n, 2), nv11 = LV(k0n, 3);

        ak00 = nk00; ak01 = nk01; ak10 = nk10; ak11 = nk11;
        av00 = nv00; av01 = nv01; av10 = nv10; av11 = nv11;
    }
#undef LK
#undef LV

    float lsum = lacc0[0] + lacc0[1] + lacc1[0] + lacc1[1];
    lsum += __shfl_xor(lsum, 32);

    // combine key halves through LDS; area per qg: 1024 floats oT + 64 floats lsum = 4352 B
    if (kh) {
        float* area = (float*)(smem + qg * 4352);
#pragma unroll
        for (int j = 0; j < 4; ++j)
            *(f32x4*)(area + j * 256 + lane * 4) =
                f32x4{oT[4 * j], oT[4 * j + 1], oT[4 * j + 2], oT[4 * j + 3]};
        area[1024 + lane] = lsum;
    }
    __syncthreads();
    if (!kh) {
        const float* area = (const float*)(smem + qg * 4352);
        lsum += area[1024 + lane];
        float inv = 1.0f / lsum;
        int b = bh >> 2, head = bh & 3;
        int n = q0 + q5;
        unsigned short* base = attnO + ((size_t)(b * NPOS + n)) * CHID + head * 32 + 4 * h;
#pragma unroll
        for (int j = 0; j < 4; ++j) {
            f32x4 r = *(const f32x4*)(area + j * 256 + lane * 4);
            unsigned long long d =
                (unsigned long long)pk2bf((oT[4 * j] + r[0]) * inv, (oT[4 * j + 1] + r[1]) * inv) |
                ((unsigned long long)pk2bf((oT[4 * j + 2] + r[2]) * inv, (oT[4 * j + 3] + r[3]) * inv) << 32);
            *(unsigned long long*)(base + 8 * j) = d;
        }
    }
}

// ---------------- kernel 4: output projection GEMM + bias, LDS-staged ----------------
__global__ __launch_bounds__(256, 4) void k_out(const unsigned short* __restrict__ wo,
                                                const unsigned short* __restrict__ attnO,
                                                const float* __restrict__ bias,
                                                float* __restrict__ out) {
    __shared__ __align__(16) unsigned char smem[2 * 12288];   // 24 KB
    int mt = blockIdx.x & 1;
    int nt = blockIdx.x >> 1;
    int wid = threadIdx.x >> 6, lane = threadIdx.x & 63;
    int quad = lane >> 4, low4 = lane & 15;
    int o0 = mt * 128, n0 = nt * 64;
    int lb = lane * 16;

    const unsigned short* srcA0 = wo + (size_t)(o0 + wid * 32 + low4) * CHID + quad * 8;
    const unsigned short* srcA1 = srcA0 + 16 * CHID;
    const unsigned short* srcB  = attnO + (size_t)(n0 + wid * 16 + low4) * CHID + quad * 8;
    int dA0 = wid * 2048, dA1 = dA0 + 1024, dB = 8192 + wid * 1024;

    async_cp16(srcA0, smem + dA0 + lb);
    async_cp16(srcA1, smem + dA1 + lb);
    async_cp16(srcB,  smem + dB  + lb);
    __syncthreads();

    f32x4 acc[2][4] = {};
    for (int c = 0; c < 4; ++c) {
        if (c < 3) {
            unsigned char* nxt = smem + ((c + 1) & 1) * 12288;
            async_cp16(srcA0 + (c + 1) * 32, nxt + dA0 + lb);
            async_cp16(srcA1 + (c + 1) * 32, nxt + dA1 + lb);
            async_cp16(srcB  + (c + 1) * 32, nxt + dB  + lb);
        }
        const unsigned char* cur = smem + (c & 1) * 12288;
        s16x8 a0 = *(const s16x8*)(cur + wid * 2048 + lb);
        s16x8 a1 = *(const s16x8*)(cur + wid * 2048 + 1024 + lb);
#pragma unroll
        for (int j = 0; j < 4; ++j) {
            s16x8 bj = *(const s16x8*)(cur + 8192 + j * 1024 + lb);
            acc[0][j] = __builtin_amdgcn_mfma_f32_16x16x32_bf16(a0, bj, acc[0][j], 0, 0, 0);
            acc[1][j] = __builtin_amdgcn_mfma_f32_16x16x32_bf16(a1, bj, acc[1][j], 0, 0, 0);
        }
        __syncthreads();
    }

#pragma unroll
    for (int i = 0; i < 2; ++i) {
        int ob = o0 + wid * 32 + i * 16 + quad * 4;
#pragma unroll
        for (int j = 0; j < 4; ++j) {
            int nG = n0 + j * 16 + low4;
            int b = nG >> 12, n = nG & 4095;
#pragma unroll
            for (int r = 0; r < 4; ++r) {
                int o = ob + r;
                out[((size_t)(b * CIN + o)) * NPOS + n] = acc[i][j][r] + bias[o];
            }
        }
    }
}

extern "C" void kernel_launch(void* const* d_in, const int* in_sizes, int n_in,
                              void* d_out, int out_size, void* d_ws, size_t ws_size,
                              hipStream_t stream) {
    const float* x    = (const float*)d_in[0];
    const float* wqkv = (const float*)d_in[1];
    const float* wout = (const float*)d_in[2];
    const float* bout = (const float*)d_in[3];
    float* out = (float*)d_out;

    unsigned short* Q       = (unsigned short*)d_ws;
    unsigned short* K       = Q + (size_t)BH * NPOS * 32;       // +4 MB
    unsigned short* V       = K + (size_t)BH * NPOS * 32;       // +4 MB
    unsigned short* attnO   = V + (size_t)BH * 32 * NPOS;       // +4 MB
    unsigned short* xT      = attnO + (size_t)NTOT * CHID;      // +4 MB
    unsigned short* wqkv_bf = xT + (size_t)NTOT * CIN;          // +8 MB
    unsigned short* wout_bf = wqkv_bf + QKV_O * CIN;            // +192 KB

    k_prep<<<TBLOCKS + (QKV_O * CIN + 255) / 256, 256, 0, stream>>>(x, xT, wqkv, wout, wqkv_bf, wout_bf);
    k_qkv<<<3 * (NTOT / 64), 256, 0, stream>>>(wqkv_bf, xT, Q, K, V);
    k_attn<<<(NPOS / 64) * BH, 256, 0, stream>>>(Q, K, V, attnO);
    k_out<<<2 * (NTOT / 64), 256, 0, stream>>>(wout_bf, attnO, bout, out);
}

// Round 3
// 155.683 us; speedup vs baseline: 1.1650x; 1.1650x over previous
//
#include <hip/hip_runtime.h>
#include <hip/hip_bf16.h>
#include <cstdint>
#include <cstddef>

// Round 13: R10 skeleton + (a) K/V stored in MFMA-fragment order by k_qkv so
// every k_attn staging load is a contiguous per-lane 16B / per-wave 4KB
// stream (was 32-line scatter), (b) counted-vmcnt barrier (stage -> vmcnt(4)
// -> s_barrier -> compute -> s_barrier) so next-iter staging stays in flight
// across the barrier instead of being drained by __syncthreads' vmcnt(0),
// (c) s_setprio(1) around MFMA pairs. LDS image & compute body identical to
// the verified R10 kernel.

#define NB 4
#define CIN 256
#define CHID 128
#define HEADS 4
#define CHEAD 32
#define NPOS 4096      // 64*64
#define BH 16          // NB*HEADS
#define NTOT 16384     // NB*NPOS
#define QKV_O 384
// 32^-0.5 * log2(e): Q pre-scaled so softmax logits feed exp2 directly
#define QSCALE_LOG2E 0.2550348229f

typedef float f32x2 __attribute__((ext_vector_type(2)));
typedef float f32x4 __attribute__((ext_vector_type(4)));
typedef float f32x16 __attribute__((ext_vector_type(16)));
typedef short s16x8 __attribute__((ext_vector_type(8)));

static __device__ __forceinline__ unsigned short f2bf(float f) {
    union { float f; unsigned u; } v; v.f = f;
    unsigned r = v.u + 0x7FFFu + ((v.u >> 16) & 1u);
    return (unsigned short)(r >> 16);
}

static __device__ __forceinline__ unsigned int pk2bf(float a, float b) {
    union { __hip_bfloat162 h; unsigned int u; } c;
    c.h = __float22bfloat162_rn(float2{a, b});
    return c.u;
}

// Exchange upper-half lanes of a with lower-half lanes of b (gfx950 VALU op).
static __device__ __forceinline__ void plswap(unsigned& a, unsigned& b) {
#if __has_builtin(__builtin_amdgcn_permlane32_swap)
    auto r = __builtin_amdgcn_permlane32_swap((int)a, (int)b, false, false);
    a = (unsigned)r[0];
    b = (unsigned)r[1];
#else
    int hh = (threadIdx.x >> 5) & 1;
    unsigned ta = (unsigned)__shfl_xor((int)a, 32);
    unsigned tb = (unsigned)__shfl_xor((int)b, 32);
    unsigned na = hh ? tb : a;
    unsigned nb = hh ? b : ta;
    a = na; b = nb;
#endif
}

static __device__ __forceinline__ s16x8 mk8(unsigned a, unsigned b, unsigned c, unsigned d) {
    union { unsigned u[4]; s16x8 v; } x;
    x.u[0] = a; x.u[1] = b; x.u[2] = c; x.u[3] = d;
    return x.v;
}

static __device__ __forceinline__ void async_cp16(const void* g, void* l) {
    __builtin_amdgcn_global_load_lds((const __attribute__((address_space(1))) unsigned int*)g,
                                     (__attribute__((address_space(3))) unsigned int*)l, 16, 0, 0);
}

#define MFMA32(a, b, c) __builtin_amdgcn_mfma_f32_32x32x16_bf16(a, b, c, 0, 0, 0)

// K fragment-order layout: K_frag[bh][g=key>>5][f=ch>>4][lane][8 shorts]
//   lane = ((ch>>3)&1)<<5 | (key&31), short j = ch&7  -> 1KB per (g,f) frag.
// V fragment-order layout: V_frag[bh][kc=key>>4][lane][8 shorts]
//   lane = ((key>>3)&1)<<5 | ch, short j = key&7      -> 1KB per kc frag.
// Both: per-bh size = NPOS*32 shorts = 256KB (same buffers as before).

// ---------------- kernel 1: transpose x -> xT bf16, fused weight convert ----------------
#define TBLOCKS (NB * (CIN / 32) * (NPOS / 32))   // 4096
__global__ __launch_bounds__(256) void k_prep(const float* __restrict__ x,
                                              unsigned short* __restrict__ xT,
                                              const float* __restrict__ wqkv,
                                              const float* __restrict__ wout,
                                              unsigned short* __restrict__ wqkv_bf,
                                              unsigned short* __restrict__ wout_bf) {
    if (blockIdx.x >= TBLOCKS) {   // weight-convert tail blocks
        int i = (blockIdx.x - TBLOCKS) * 256 + threadIdx.x;
        if (i < QKV_O * CIN) wqkv_bf[i] = f2bf(wqkv[i]);
        if (i < CIN * CHID)  wout_bf[i] = f2bf(wout[i]);
        return;
    }
    __shared__ float tile[32][33];
    const int ntiles = NPOS / 32;   // 128
    const int ctiles = CIN / 32;    // 8
    int b   = blockIdx.x / (ntiles * ctiles);
    int rem = blockIdx.x % (ntiles * ctiles);
    int ct = rem / ntiles;
    int nt = rem % ntiles;
    int c0 = ct * 32, n0 = nt * 32;
    int tc = threadIdx.x / 32;
    int tn = threadIdx.x % 32;
    const float* xb = x + (size_t)b * CIN * NPOS;
#pragma unroll
    for (int it = 0; it < 4; ++it) {
        int c = tc + it * 8;
        tile[c][tn] = xb[(size_t)(c0 + c) * NPOS + n0 + tn];
    }
    __syncthreads();
    unsigned short* xTb = xT + (size_t)b * NPOS * CIN;
#pragma unroll
    for (int it = 0; it < 4; ++it) {
        int n = tc + it * 8;
        xTb[(size_t)(n0 + n) * CIN + c0 + tn] = f2bf(tile[tn][n]);
    }
}

// ---------------- kernel 2: QKV projection GEMM, LDS-staged ----------------
// mt==0 -> pure Q, mt==1 -> K in fragment order, mt==2 -> V in fragment order
__global__ __launch_bounds__(256, 4) void k_qkv(const unsigned short* __restrict__ wq,
                                                const unsigned short* __restrict__ xT,
                                                unsigned short* __restrict__ Q,
                                                unsigned short* __restrict__ K,
                                                unsigned short* __restrict__ V) {
    __shared__ __align__(16) unsigned char smem[2 * 12288];   // 24 KB
    int mt = blockIdx.x % 3;
    int nt = blockIdx.x / 3;
    int wid = threadIdx.x >> 6, lane = threadIdx.x & 63;
    int quad = lane >> 4, low4 = lane & 15;
    int o0 = mt * 128, n0 = nt * 64;
    int lb = lane * 16;

    const unsigned short* srcA0 = wq + (size_t)(o0 + wid * 32 + low4) * CIN + quad * 8;
    const unsigned short* srcA1 = srcA0 + 16 * CIN;
    const unsigned short* srcB  = xT + (size_t)(n0 + wid * 16 + low4) * CIN + quad * 8;
    int dA0 = wid * 2048, dA1 = dA0 + 1024, dB = 8192 + wid * 1024;

    async_cp16(srcA0, smem + dA0 + lb);
    async_cp16(srcA1, smem + dA1 + lb);
    async_cp16(srcB,  smem + dB  + lb);
    __syncthreads();

    f32x4 acc[2][4] = {};
    for (int c = 0; c < 8; ++c) {
        if (c < 7) {
            unsigned char* nxt = smem + ((c + 1) & 1) * 12288;
            async_cp16(srcA0 + (c + 1) * 32, nxt + dA0 + lb);
            async_cp16(srcA1 + (c + 1) * 32, nxt + dA1 + lb);
            async_cp16(srcB  + (c + 1) * 32, nxt + dB  + lb);
        }
        const unsigned char* cur = smem + (c & 1) * 12288;
        s16x8 a0 = *(const s16x8*)(cur + wid * 2048 + lb);
        s16x8 a1 = *(const s16x8*)(cur + wid * 2048 + 1024 + lb);
#pragma unroll
        for (int j = 0; j < 4; ++j) {
            s16x8 bj = *(const s16x8*)(cur + 8192 + j * 1024 + lb);
            acc[0][j] = __builtin_amdgcn_mfma_f32_16x16x32_bf16(a0, bj, acc[0][j], 0, 0, 0);
            acc[1][j] = __builtin_amdgcn_mfma_f32_16x16x32_bf16(a1, bj, acc[1][j], 0, 0, 0);
        }
        __syncthreads();
    }

    if (mt == 0) {
        // Q: layout unchanged [bh][n][32ch]
#pragma unroll
        for (int i = 0; i < 2; ++i) {
            int ol = wid * 32 + i * 16 + quad * 4;
            int head = ol >> 5, ch = ol & 31;
#pragma unroll
            for (int j = 0; j < 4; ++j) {
                int nG = n0 + j * 16 + low4;
                int b = nG >> 12, n = nG & 4095;
                f32x4 v = acc[i][j];
                unsigned long long d =
                    (unsigned long long)pk2bf(v[0] * QSCALE_LOG2E, v[1] * QSCALE_LOG2E) |
                    ((unsigned long long)pk2bf(v[2] * QSCALE_LOG2E, v[3] * QSCALE_LOG2E) << 32);
                *(unsigned long long*)(Q + ((size_t)(b * 4 + head) * NPOS + n) * 32 + ch) = d;
            }
        }
    } else if (mt == 1) {
        // K: fragment order. acc[i][j][r] = channel (ol+r), position nG.
#pragma unroll
        for (int i = 0; i < 2; ++i) {
            int ol = wid * 32 + i * 16 + quad * 4;
            int head = ol >> 5, c0 = ol & 31;
            int f = c0 >> 4, hh = (c0 >> 3) & 1, j8 = c0 & 7;   // j8 in {0,4}
#pragma unroll
            for (int j = 0; j < 4; ++j) {
                int nG = n0 + j * 16 + low4;
                int b = nG >> 12, n = nG & 4095;
                int bh = b * 4 + head;
                f32x4 v = acc[i][j];
                unsigned long long d =
                    (unsigned long long)pk2bf(v[0], v[1]) |
                    ((unsigned long long)pk2bf(v[2], v[3]) << 32);
                size_t addr = (((size_t)bh * 128 + (n >> 5)) * 2 + f) * 512
                            + (size_t)((((hh << 5) | (n & 31)) << 3) + j8);
                *(unsigned long long*)(K + addr) = d;
            }
        }
    } else {
        // V: transpose 128(ch) x 64(n) through LDS, then store fragment-order
        unsigned short* vt = (unsigned short*)smem;   // [128][80] shorts (20 KB), rows 16B-aligned
#pragma unroll
        for (int i = 0; i < 2; ++i) {
            int ol = wid * 32 + i * 16 + quad * 4;
#pragma unroll
            for (int j = 0; j < 4; ++j) {
                int col = j * 16 + low4;
#pragma unroll
                for (int r = 0; r < 4; ++r) vt[(ol + r) * 80 + col] = f2bf(acc[i][j][r]);
            }
        }
        __syncthreads();
        int b = n0 >> 12, nbase = n0 & 4095;
#pragma unroll
        for (int rep = 0; rep < 4; ++rep) {
            int idx = rep * 256 + threadIdx.x;
            int row = idx >> 3, c8 = idx & 7;
            s16x8 val = *(const s16x8*)(vt + row * 80 + c8 * 8);   // keys nstart..+8, channel row
            int head = row >> 5, ch = row & 31;
            int bh = b * 4 + head;
            int nstart = nbase + c8 * 8;
            int kc = nstart >> 4, hh = (nstart >> 3) & 1;
            *(s16x8*)(V + ((size_t)(bh * 256 + kc) * 64 + ((hh << 5) | ch)) * 8) = val;
        }
    }
}

// ---------------- kernel 3: attention, 32 queries/wave, split-K x2, 1024 blocks ----------------
// Grid: qt(64) x bh(16) -> all 64 same-bh blocks on one XCD (K/V ~1MB, L2-hot).
// Block: 4 waves = qg(2) x kh(2), 4 blocks/CU. Per 64-key iter, the kh wave
// pair stages K(4KB)+V(4KB) as CONTIGUOUS fragment-order streams into dbuf
// LDS. Counted-vmcnt sync: stage(it+1) -> vmcnt(4) [iter-it data landed,
// it+1 stays in flight] -> s_barrier -> compute -> s_barrier [WAR protect].
// Compute body identical to the verified R10 kernel; setprio(1) brackets
// MFMA pairs.
__global__ __launch_bounds__(256, 4) void k_attn(const unsigned short* __restrict__ Q,
                                                 const unsigned short* __restrict__ K,
                                                 const unsigned short* __restrict__ V,
                                                 unsigned short* __restrict__ attnO) {
    __shared__ __align__(16) unsigned char smem[2 * 16384];   // 32 KB dbuf; combine reuses buf0
    int bh = blockIdx.x & 15;
    int qt = blockIdx.x >> 4;          // 0..63
    int wid = threadIdx.x >> 6;        // 0..3
    int lane = threadIdx.x & 63;
    int q5 = lane & 31, h = lane >> 5;
    int qg = wid & 1, kh = wid >> 1;
    int q0 = qt * 64 + qg * 32;
    int khk = kh * 2048;

    const unsigned short* Qp = Q + (size_t)bh * NPOS * 32;

    // Q B-frags (n=query q5, k=ch chunks 0..15 / 16..31)
    s16x8 bq0 = *(const s16x8*)(Qp + (size_t)(q0 + q5) * 32 + h * 8);
    s16x8 bq1 = *(const s16x8*)(Qp + (size_t)(q0 + q5) * 32 + 16 + h * 8);

    // Fragment-order bases: per-lane 16B slices of contiguous 1KB frags.
    const unsigned short* pKf = K + (size_t)bh * 131072 + lane * 8;
    const unsigned short* pVf = V + (size_t)bh * 131072 + lane * 8;

    auto stage = [&](int bufi, int k0) {
        unsigned char* wb = smem + bufi * 16384 + kh * 8192;
        if (qg == 0) {   // K: frags (g0,f0)(g0,f1)(g0+1,f0)(g0+1,f1) — contiguous 4KB
            const unsigned short* p = pKf + (size_t)(k0 >> 5) * 1024;
            async_cp16(p,        wb);
            async_cp16(p + 512,  wb + 1024);
            async_cp16(p + 1024, wb + 2048);
            async_cp16(p + 1536, wb + 3072);
        } else {         // V: frags kc0..kc0+3 — contiguous 4KB
            const unsigned short* p = pVf + (size_t)(k0 >> 4) * 512;
            async_cp16(p,        wb + 4096);
            async_cp16(p + 512,  wb + 5120);
            async_cp16(p + 1024, wb + 6144);
            async_cp16(p + 1536, wb + 7168);
        }
    };

    f32x16 oT = {};
    f32x2 lacc0 = {0.0f, 0.0f}, lacc1 = {0.0f, 0.0f};
    const int lby = lane * 16;

    stage(0, khk);

#pragma unroll 1
    for (int it = 0; it < 32; ++it) {
        if (it + 1 < 32) {
            stage((it + 1) & 1, khk + (it + 1) * 64);
            asm volatile("s_waitcnt vmcnt(4)" ::: "memory");   // iter-it staging landed; it+1 in flight
        } else {
            asm volatile("s_waitcnt vmcnt(0)" ::: "memory");
        }
        asm volatile("s_barrier" ::: "memory");

        const unsigned char* kb = smem + (it & 1) * 16384 + kh * 8192;
#pragma unroll
        for (int t = 0; t < 2; ++t) {
            s16x8 ak0 = *(const s16x8*)(kb + t * 2048 + lby);
            s16x8 ak1 = *(const s16x8*)(kb + t * 2048 + 1024 + lby);
            f32x16 s = {};
            __builtin_amdgcn_s_setprio(1);
            s = MFMA32(ak0, bq0, s);
            s = MFMA32(ak1, bq1, s);
            __builtin_amdgcn_s_setprio(0);
            unsigned p[8];
#pragma unroll
            for (int i = 0; i < 8; ++i) {
                float e0 = __builtin_amdgcn_exp2f(s[2 * i]);
                float e1 = __builtin_amdgcn_exp2f(s[2 * i + 1]);
                f32x2 e = {e0, e1};
                if (i & 1) lacc0 += e;
                else       lacc1 += e;
                p[i] = pk2bf(e0, e1);
            }
            // C-layout -> B-operand fragment transform (pure VALU)
            plswap(p[0], p[2]); plswap(p[1], p[3]);
            plswap(p[4], p[6]); plswap(p[5], p[7]);
            s16x8 bplo = mk8(p[0], p[1], p[2], p[3]);
            s16x8 bphi = mk8(p[4], p[5], p[6], p[7]);

            s16x8 av0 = *(const s16x8*)(kb + 4096 + (2 * t) * 1024 + lby);
            s16x8 av1 = *(const s16x8*)(kb + 4096 + (2 * t + 1) * 1024 + lby);
            __builtin_amdgcn_s_setprio(1);
            oT = MFMA32(av0, bplo, oT);
            oT = MFMA32(av1, bphi, oT);
            __builtin_amdgcn_s_setprio(0);
        }
        asm volatile("s_barrier" ::: "memory");   // WAR: buf (it&1) free to restage next iter
    }

    float lsum = lacc0[0] + lacc0[1] + lacc1[0] + lacc1[1];
    lsum += __shfl_xor(lsum, 32);

    // combine key halves through LDS (buf0 low area is dead: compute(31) used buf1)
    // area per qg: 1024 floats oT + 64 floats lsum = 4352 B
    if (kh) {
        float* area = (float*)(smem + qg * 4352);
#pragma unroll
        for (int j = 0; j < 4; ++j)
            *(f32x4*)(area + j * 256 + lane * 4) =
                f32x4{oT[4 * j], oT[4 * j + 1], oT[4 * j + 2], oT[4 * j + 3]};
        area[1024 + lane] = lsum;
    }
    __syncthreads();
    if (!kh) {
        const float* area = (const float*)(smem + qg * 4352);
        lsum += area[1024 + lane];
        float inv = 1.0f / lsum;
        int b = bh >> 2, head = bh & 3;
        int n = q0 + q5;
        unsigned short* base = attnO + ((size_t)(b * NPOS + n)) * CHID + head * 32 + 4 * h;
#pragma unroll
        for (int j = 0; j < 4; ++j) {
            f32x4 r = *(const f32x4*)(area + j * 256 + lane * 4);
            unsigned long long d =
                (unsigned long long)pk2bf((oT[4 * j] + r[0]) * inv, (oT[4 * j + 1] + r[1]) * inv) |
                ((unsigned long long)pk2bf((oT[4 * j + 2] + r[2]) * inv, (oT[4 * j + 3] + r[3]) * inv) << 32);
            *(unsigned long long*)(base + 8 * j) = d;
        }
    }
}

// ---------------- kernel 4: output projection GEMM + bias, LDS-staged ----------------
__global__ __launch_bounds__(256, 4) void k_out(const unsigned short* __restrict__ wo,
                                                const unsigned short* __restrict__ attnO,
                                                const float* __restrict__ bias,
                                                float* __restrict__ out) {
    __shared__ __align__(16) unsigned char smem[2 * 12288];   // 24 KB
    int mt = blockIdx.x & 1;
    int nt = blockIdx.x >> 1;
    int wid = threadIdx.x >> 6, lane = threadIdx.x & 63;
    int quad = lane >> 4, low4 = lane & 15;
    int o0 = mt * 128, n0 = nt * 64;
    int lb = lane * 16;

    const unsigned short* srcA0 = wo + (size_t)(o0 + wid * 32 + low4) * CHID + quad * 8;
    const unsigned short* srcA1 = srcA0 + 16 * CHID;
    const unsigned short* srcB  = attnO + (size_t)(n0 + wid * 16 + low4) * CHID + quad * 8;
    int dA0 = wid * 2048, dA1 = dA0 + 1024, dB = 8192 + wid * 1024;

    async_cp16(srcA0, smem + dA0 + lb);
    async_cp16(srcA1, smem + dA1 + lb);
    async_cp16(srcB,  smem + dB  + lb);
    __syncthreads();

    f32x4 acc[2][4] = {};
    for (int c = 0; c < 4; ++c) {
        if (c < 3) {
            unsigned char* nxt = smem + ((c + 1) & 1) * 12288;
            async_cp16(srcA0 + (c + 1) * 32, nxt + dA0 + lb);
            async_cp16(srcA1 + (c + 1) * 32, nxt + dA1 + lb);
            async_cp16(srcB  + (c + 1) * 32, nxt + dB  + lb);
        }
        const unsigned char* cur = smem + (c & 1) * 12288;
        s16x8 a0 = *(const s16x8*)(cur + wid * 2048 + lb);
        s16x8 a1 = *(const s16x8*)(cur + wid * 2048 + 1024 + lb);
#pragma unroll
        for (int j = 0; j < 4; ++j) {
            s16x8 bj = *(const s16x8*)(cur + 8192 + j * 1024 + lb);
            acc[0][j] = __builtin_amdgcn_mfma_f32_16x16x32_bf16(a0, bj, acc[0][j], 0, 0, 0);
            acc[1][j] = __builtin_amdgcn_mfma_f32_16x16x32_bf16(a1, bj, acc[1][j], 0, 0, 0);
        }
        __syncthreads();
    }

#pragma unroll
    for (int i = 0; i < 2; ++i) {
        int ob = o0 + wid * 32 + i * 16 + quad * 4;
#pragma unroll
        for (int j = 0; j < 4; ++j) {
            int nG = n0 + j * 16 + low4;
            int b = nG >> 12, n = nG & 4095;
#pragma unroll
            for (int r = 0; r < 4; ++r) {
                int o = ob + r;
                out[((size_t)(b * CIN + o)) * NPOS + n] = acc[i][j][r] + bias[o];
            }
        }
    }
}

extern "C" void kernel_launch(void* const* d_in, const int* in_sizes, int n_in,
                              void* d_out, int out_size, void* d_ws, size_t ws_size,
                              hipStream_t stream) {
    const float* x    = (const float*)d_in[0];
    const float* wqkv = (const float*)d_in[1];
    const float* wout = (const float*)d_in[2];
    const float* bout = (const float*)d_in[3];
    float* out = (float*)d_out;

    unsigned short* Q       = (unsigned short*)d_ws;
    unsigned short* K       = Q + (size_t)BH * NPOS * 32;       // +4 MB (fragment order)
    unsigned short* V       = K + (size_t)BH * NPOS * 32;       // +4 MB (fragment order)
    unsigned short* attnO   = V + (size_t)BH * 32 * NPOS;       // +4 MB
    unsigned short* xT      = attnO + (size_t)NTOT * CHID;      // +4 MB
    unsigned short* wqkv_bf = xT + (size_t)NTOT * CIN;          // +8 MB
    unsigned short* wout_bf = wqkv_bf + QKV_O * CIN;            // +192 KB

    k_prep<<<TBLOCKS + (QKV_O * CIN + 255) / 256, 256, 0, stream>>>(x, xT, wqkv, wout, wqkv_bf, wout_bf);
    k_qkv<<<3 * (NTOT / 64), 256, 0, stream>>>(wqkv_bf, xT, Q, K, V);
    k_attn<<<(NPOS / 64) * BH, 256, 0, stream>>>(Q, K, V, attnO);
    k_out<<<2 * (NTOT / 64), 256, 0, stream>>>(wout_bf, attnO, bout, out);
}